// Round 1
// baseline (1514.646 us; speedup 1.0000x reference)
//
#include <hip/hip_runtime.h>
#include <math.h>

#define EPS 1e-5f

namespace {

constexpr int Bn = 2, Sn = 2048, Cn = 768;
constexpr float INV_BS = 1.0f / 4096.0f;     // B*S
constexpr float INV_PAIR = 1.0f / 32768.0f;  // B*SP*SP

// ---- per-channel sum of squares, 128-ch (pair_x) ----
__global__ void pair_sumsq_k(const float* __restrict__ p, float* __restrict__ out) {
  int r0 = blockIdx.x * 128;
  float acc = 0.f;
  for (int r = 0; r < 128; ++r) {
    float v = p[(size_t)(r0 + r) * 128 + threadIdx.x];
    acc += v * v;
  }
  atomicAdd(&out[threadIdx.x], acc);
}

// ---- per-channel sum of squares, 768-ch ----
__global__ void ch_sumsq768_k(const float* __restrict__ a, float* __restrict__ out) {
  int r0 = blockIdx.x * 16;
  int c = threadIdx.x;
  float acc = 0.f;
  for (int r = 0; r < 16; ++r) {
    float v = a[(size_t)(r0 + r) * 768 + c];
    acc += v * v;
  }
  atomicAdd(&out[c], acc);
}

// ---- pair bias: rms_bn -> gelu -> fc [2,128] -> pb2[b,i,j,g] ----
__global__ void pair_bias_k(const float* __restrict__ p, const float* __restrict__ ps,
                            const float* __restrict__ g, const float* __restrict__ w,
                            float* __restrict__ pb2) {
  int idx = blockIdx.x * 256 + threadIdx.x;  // (b,i,j) flat, 32768 total
  const float* row = p + (size_t)idx * 128;
  float a0 = 0.f, a1 = 0.f;
  for (int c = 0; c < 128; ++c) {
    float sc = rsqrtf(ps[c] * INV_PAIR + EPS) * g[c];
    float v = row[c] * sc;
    float ge = 0.5f * v * (1.f + erff(v * 0.70710678118654752f));
    a0 += ge * w[c];
    a1 += ge * w[128 + c];
  }
  pb2[(size_t)idx * 2 + 0] = a0;
  pb2[(size_t)idx * 2 + 1] = a1;
}

// ---- generic NT GEMM: out[m,n] = act(sum_k A[m,k]*cs[k]*W[n,k] + bias[n]) ----
// cs[k] = rsqrt(sums[k]*invcount + EPS)*gamma[k] if sums else 1
template <bool RELU>
__global__ __launch_bounds__(256) void gemm_nt_k(
    const float* __restrict__ A, const float* __restrict__ W,
    float* __restrict__ out, int N, int K,
    const float* __restrict__ sums, const float* __restrict__ gamma,
    float invcount, const float* __restrict__ bias) {
  __shared__ float As[32][68];
  __shared__ float Ws[32][68];
  const int m0 = blockIdx.y * 64, n0 = blockIdx.x * 64;
  const int tid = threadIdx.x;
  const int tx = tid & 15, ty = tid >> 4;
  const int row = tid >> 3;
  const int kc = (tid & 7) * 4;
  float acc[4][4] = {};
  for (int k0 = 0; k0 < K; k0 += 32) {
    float4 sc4 = {1.f, 1.f, 1.f, 1.f};
    if (sums) {
      sc4.x = rsqrtf(sums[k0 + kc + 0] * invcount + EPS) * gamma[k0 + kc + 0];
      sc4.y = rsqrtf(sums[k0 + kc + 1] * invcount + EPS) * gamma[k0 + kc + 1];
      sc4.z = rsqrtf(sums[k0 + kc + 2] * invcount + EPS) * gamma[k0 + kc + 2];
      sc4.w = rsqrtf(sums[k0 + kc + 3] * invcount + EPS) * gamma[k0 + kc + 3];
    }
#pragma unroll
    for (int half = 0; half < 2; ++half) {
      int r = row + half * 32;
      float4 av = *(const float4*)&A[(size_t)(m0 + r) * K + k0 + kc];
      if (sums) { av.x *= sc4.x; av.y *= sc4.y; av.z *= sc4.z; av.w *= sc4.w; }
      As[kc + 0][r] = av.x; As[kc + 1][r] = av.y; As[kc + 2][r] = av.z; As[kc + 3][r] = av.w;
      float4 wv = *(const float4*)&W[(size_t)(n0 + r) * K + k0 + kc];
      Ws[kc + 0][r] = wv.x; Ws[kc + 1][r] = wv.y; Ws[kc + 2][r] = wv.z; Ws[kc + 3][r] = wv.w;
    }
    __syncthreads();
#pragma unroll
    for (int k = 0; k < 32; ++k) {
      float4 a4 = *(const float4*)&As[k][ty * 4];
      float4 b4 = *(const float4*)&Ws[k][tx * 4];
      acc[0][0] += a4.x * b4.x; acc[0][1] += a4.x * b4.y; acc[0][2] += a4.x * b4.z; acc[0][3] += a4.x * b4.w;
      acc[1][0] += a4.y * b4.x; acc[1][1] += a4.y * b4.y; acc[1][2] += a4.y * b4.z; acc[1][3] += a4.y * b4.w;
      acc[2][0] += a4.z * b4.x; acc[2][1] += a4.z * b4.y; acc[2][2] += a4.z * b4.z; acc[2][3] += a4.z * b4.w;
      acc[3][0] += a4.w * b4.x; acc[3][1] += a4.w * b4.y; acc[3][2] += a4.w * b4.z; acc[3][3] += a4.w * b4.w;
    }
    __syncthreads();
  }
#pragma unroll
  for (int i = 0; i < 4; ++i) {
    float b0 = 0.f, b1 = 0.f, b2 = 0.f, b3 = 0.f;
    if (bias) {
      b0 = bias[n0 + tx * 4 + 0]; b1 = bias[n0 + tx * 4 + 1];
      b2 = bias[n0 + tx * 4 + 2]; b3 = bias[n0 + tx * 4 + 3];
    }
    float4 o;
    o.x = acc[i][0] + b0; o.y = acc[i][1] + b1; o.z = acc[i][2] + b2; o.w = acc[i][3] + b3;
    if (RELU) {
      o.x = fmaxf(o.x, 0.f); o.y = fmaxf(o.y, 0.f); o.z = fmaxf(o.z, 0.f); o.w = fmaxf(o.w, 0.f);
    }
    *(float4*)&out[(size_t)(m0 + ty * 4 + i) * N + n0 + tx * 4] = o;
  }
}

// ---- per-head LayerNorm + RoPE + transpose to [B,H,S,D] ----
__global__ __launch_bounds__(128) void ln_rope_k(
    const float* __restrict__ qtmp, const float* __restrict__ ktmp, const float* __restrict__ vtmp,
    const float* __restrict__ qg, const float* __restrict__ qb,
    const float* __restrict__ kg, const float* __restrict__ kb,
    const float* __restrict__ vg, const float* __restrict__ vb,
    float* __restrict__ q_t, float* __restrict__ k_t, float* __restrict__ v_t) {
  const int bs = blockIdx.x;        // b*S+s
  const int slot = blockIdx.y;      // 0..7 q, 8..11 k, 12..15 v
  const int s = bs & (Sn - 1);
  const int b = bs >> 11;
  const int tid = threadIdx.x;
  const float* src; const float* g; const float* be; float* dst; bool dorope;
  if (slot < 8) {
    src = qtmp + (size_t)bs * 1024 + slot * 128;
    g = qg; be = qb;
    dst = q_t + ((size_t)(b * 8 + slot) * Sn + s) * 128;
    dorope = true;
  } else if (slot < 12) {
    int h = slot - 8;
    src = ktmp + (size_t)bs * 512 + h * 128;
    g = kg; be = kb;
    dst = k_t + ((size_t)(b * 4 + h) * Sn + s) * 128;
    dorope = true;
  } else {
    int h = slot - 12;
    src = vtmp + (size_t)bs * 512 + h * 128;
    g = vg; be = vb;
    dst = v_t + ((size_t)(b * 4 + h) * Sn + s) * 128;
    dorope = false;
  }
  __shared__ float sh[128];
  __shared__ float red[4];
  float v = src[tid];
  float sum = v;
#pragma unroll
  for (int o = 32; o >= 1; o >>= 1) sum += __shfl_xor(sum, o);
  if ((tid & 63) == 0) red[tid >> 6] = sum;
  __syncthreads();
  float mean = (red[0] + red[1]) * (1.f / 128.f);
  float d = v - mean;
  float s2 = d * d;
#pragma unroll
  for (int o = 32; o >= 1; o >>= 1) s2 += __shfl_xor(s2, o);
  if ((tid & 63) == 0) red[2 + (tid >> 6)] = s2;
  __syncthreads();
  float var = (red[2] + red[3]) * (1.f / 128.f);
  float val = d * rsqrtf(var + EPS) * g[tid] + be[tid];
  if (dorope) {
    sh[tid] = val;
    __syncthreads();
    int i = tid >> 1;
    const float kGeo = logf(1985.0f) * (1.0f / 63.0f);  // AlphaGenome schedule
    float inv = 1.0f / ((float)i + expf((float)i * kGeo));
    float th = (float)s * inv;
    float cs = cosf(th), sn = sinf(th);
    float rot = (tid & 1) ? sh[tid - 1] : -sh[tid + 1];
    val = val * cs + rot * sn;
  }
  dst[tid] = val;
}

// ---- flash attention with pair bias + tanh softcap ----
__global__ __launch_bounds__(256) void flash_k(
    const float* __restrict__ q_t, const float* __restrict__ k_t,
    const float* __restrict__ v_t, const float* __restrict__ pb2,
    float* __restrict__ o_t) {
  __shared__ float Qs[64][132];
  __shared__ float Ks[64][132];
  __shared__ float Vs[64][132];
  __shared__ float Ss[64][68];
  __shared__ float mrow[64], lrow[64], crow[64];
  const int s0 = blockIdx.x * 64;
  const int bh = blockIdx.y;  // b*8+h
  const int b = bh >> 3, h = bh & 7;
  const int kv = h & 3, grp = h >> 2;
  const float* qbase = q_t + ((size_t)bh * Sn + s0) * 128;
  const float* kbase = k_t + (size_t)(b * 4 + kv) * Sn * 128;
  const float* vbase = v_t + (size_t)(b * 4 + kv) * Sn * 128;
  const int tid = threadIdx.x;
  const int tx = tid & 15, ty = tid >> 4;
#pragma unroll
  for (int u = 0; u < 8; ++u) {
    int fi = u * 256 + tid;
    int r = fi >> 5, c = (fi & 31) * 4;
    *(float4*)&Qs[r][c] = *(const float4*)&qbase[(size_t)r * 128 + c];
  }
  if (tid < 64) { mrow[tid] = -1e30f; lrow[tid] = 0.f; }
  float y[4][8] = {};
  const float rs = 0.088388347648318447f;  // 1/sqrt(128)
  __syncthreads();
  for (int t0 = 0; t0 < Sn; t0 += 64) {
#pragma unroll
    for (int u = 0; u < 8; ++u) {
      int fi = u * 256 + tid;
      int r = fi >> 5, c = (fi & 31) * 4;
      *(float4*)&Ks[r][c] = *(const float4*)&kbase[(size_t)(t0 + r) * 128 + c];
      *(float4*)&Vs[r][c] = *(const float4*)&vbase[(size_t)(t0 + r) * 128 + c];
    }
    __syncthreads();
    // S-tile: rows ty+16i, cols tx+16j (strided => conflict-light, uniform bias)
    float acc[4][4] = {};
    for (int c = 0; c < 128; c += 4) {
      float4 q4[4], k4[4];
#pragma unroll
      for (int i = 0; i < 4; ++i) q4[i] = *(const float4*)&Qs[ty + 16 * i][c];
#pragma unroll
      for (int j = 0; j < 4; ++j) k4[j] = *(const float4*)&Ks[tx + 16 * j][c];
#pragma unroll
      for (int i = 0; i < 4; ++i)
#pragma unroll
        for (int j = 0; j < 4; ++j)
          acc[i][j] += q4[i].x * k4[j].x + q4[i].y * k4[j].y + q4[i].z * k4[j].z + q4[i].w * k4[j].w;
    }
#pragma unroll
    for (int i = 0; i < 4; ++i) {
#pragma unroll
      for (int j = 0; j < 4; ++j) {
        float bias = pb2[(((size_t)b * 128 + (s0 >> 4) + i) * 128 + (t0 >> 4) + j) * 2 + grp];
        float l = acc[i][j] * rs + bias;
        l = tanhf(l * 0.2f) * 5.0f;
        Ss[ty + 16 * i][tx + 16 * j] = l;
      }
    }
    __syncthreads();
    // online softmax: 4 threads per row
    {
      int r = tid >> 2, part = tid & 3;
      float mx = -1e30f;
#pragma unroll
      for (int j = 0; j < 16; ++j) mx = fmaxf(mx, Ss[r][part * 16 + j]);
      mx = fmaxf(mx, __shfl_xor(mx, 1));
      mx = fmaxf(mx, __shfl_xor(mx, 2));
      float mold = mrow[r];
      float mnew = fmaxf(mold, mx);
      float psum = 0.f;
#pragma unroll
      for (int j = 0; j < 16; ++j) {
        float p = __expf(Ss[r][part * 16 + j] - mnew);
        Ss[r][part * 16 + j] = p;
        psum += p;
      }
      psum += __shfl_xor(psum, 1);
      psum += __shfl_xor(psum, 2);
      if (part == 0) {
        float corr = __expf(mold - mnew);
        crow[r] = corr;
        lrow[r] = lrow[r] * corr + psum;
        mrow[r] = mnew;
      }
    }
    __syncthreads();
    // y += P @ V ; y rows ty*4+i, cols {tx*4..+3, 64+tx*4..+3}
#pragma unroll
    for (int i = 0; i < 4; ++i) {
      float cr = crow[ty * 4 + i];
#pragma unroll
      for (int j = 0; j < 8; ++j) y[i][j] *= cr;
    }
    for (int t = 0; t < 64; ++t) {
      float4 v0 = *(const float4*)&Vs[t][tx * 4];
      float4 v1 = *(const float4*)&Vs[t][64 + tx * 4];
#pragma unroll
      for (int i = 0; i < 4; ++i) {
        float p = Ss[ty * 4 + i][t];
        y[i][0] += p * v0.x; y[i][1] += p * v0.y; y[i][2] += p * v0.z; y[i][3] += p * v0.w;
        y[i][4] += p * v1.x; y[i][5] += p * v1.y; y[i][6] += p * v1.z; y[i][7] += p * v1.w;
      }
    }
    __syncthreads();
  }
#pragma unroll
  for (int i = 0; i < 4; ++i) {
    float inv = 1.0f / lrow[ty * 4 + i];
    float* orow = o_t + ((size_t)bh * Sn + s0 + ty * 4 + i) * 128;
    float4 o0, o1;
    o0.x = y[i][0] * inv; o0.y = y[i][1] * inv; o0.z = y[i][2] * inv; o0.w = y[i][3] * inv;
    o1.x = y[i][4] * inv; o1.y = y[i][5] * inv; o1.z = y[i][6] * inv; o1.w = y[i][7] * inv;
    *(float4*)&orow[tx * 4] = o0;
    *(float4*)&orow[64 + tx * 4] = o1;
  }
}

// ---- out = base + delta * rsqrt(sums/4096+eps)*g ----
__global__ void add_scale_k(const float* __restrict__ base, const float* __restrict__ delta,
                            const float* __restrict__ sums, const float* __restrict__ g,
                            float* __restrict__ out) {
  const int c = threadIdx.x;
  const float sc = rsqrtf(sums[c] * INV_BS + EPS) * g[c];
  const int r0 = blockIdx.x * 16;
  for (int r = 0; r < 16; ++r) {
    size_t idx = (size_t)(r0 + r) * 768 + c;
    out[idx] = base[idx] + delta[idx] * sc;
  }
}

}  // namespace

extern "C" void kernel_launch(void* const* d_in, const int* in_sizes, int n_in,
                              void* d_out, int out_size, void* d_ws, size_t ws_size,
                              hipStream_t stream) {
  const float* x       = (const float*)d_in[0];
  const float* pair_x  = (const float*)d_in[1];
  const float* ab_bn_g = (const float*)d_in[2];
  const float* ab_fc_w = (const float*)d_in[3];
  const float* bn1_g   = (const float*)d_in[4];
  const float* wq      = (const float*)d_in[5];
  const float* wk      = (const float*)d_in[6];
  const float* wv      = (const float*)d_in[7];
  const float* qn_g    = (const float*)d_in[8];
  const float* qn_b    = (const float*)d_in[9];
  const float* kn_g    = (const float*)d_in[10];
  const float* kn_b    = (const float*)d_in[11];
  const float* vn_g    = (const float*)d_in[12];
  const float* vn_b    = (const float*)d_in[13];
  const float* wo      = (const float*)d_in[14];
  const float* bo      = (const float*)d_in[15];
  const float* bn2_g   = (const float*)d_in[16];
  const float* mbn1_g  = (const float*)d_in[17];
  const float* w1      = (const float*)d_in[18];
  const float* b1      = (const float*)d_in[19];
  const float* w2      = (const float*)d_in[20];
  const float* b2      = (const float*)d_in[21];
  const float* mbn2_g  = (const float*)d_in[22];
  float* out = (float*)d_out;
  float* ws = (float*)d_ws;

  // ws layout (floats); total 16,846,848 floats = 64.3 MiB, with liveness-based reuse
  float* ps    = ws + 0;         // 128   pair sumsq
  float* xs    = ws + 256;       // 768   x sumsq
  float* es    = ws + 1024;      // 768   proj sumsq
  float* x2s   = ws + 2048;      // 768   x2 sumsq
  float* fs    = ws + 3072;      // 768   proj2 sumsq
  float* pb2   = ws + 4096;      // 65536 [B,128,128,2]
  float* qtmp  = ws + 69632;     // 4.19M ; later attn_out, then h (spans into ktmp)
  float* ktmp  = ws + 4263936;   // 2.10M ; later proj
  float* vtmp  = ws + 6361088;   // 2.10M
  float* q_t   = ws + 8458240;   // 4.19M ; later proj2
  float* k_t   = ws + 12652544;  // 2.10M ; later x2 (spans into v_t)
  float* v_t   = ws + 14749696;  // 2.10M
  float* attn  = qtmp;
  float* proj  = ktmp;
  float* x2    = k_t;
  float* hbuf  = qtmp;
  float* proj2 = q_t;

  (void)hipMemsetAsync(ws, 0, 4096 * sizeof(float), stream);

  pair_sumsq_k<<<256, 128, 0, stream>>>(pair_x, ps);
  pair_bias_k<<<128, 256, 0, stream>>>(pair_x, ps, ab_bn_g, ab_fc_w, pb2);
  ch_sumsq768_k<<<256, 768, 0, stream>>>(x, xs);
  gemm_nt_k<false><<<dim3(16, 64), 256, 0, stream>>>(x, wq, qtmp, 1024, 768, xs, bn1_g, INV_BS, nullptr);
  gemm_nt_k<false><<<dim3(8, 64), 256, 0, stream>>>(x, wk, ktmp, 512, 768, xs, bn1_g, INV_BS, nullptr);
  gemm_nt_k<false><<<dim3(8, 64), 256, 0, stream>>>(x, wv, vtmp, 512, 768, xs, bn1_g, INV_BS, nullptr);
  ln_rope_k<<<dim3(4096, 16), 128, 0, stream>>>(qtmp, ktmp, vtmp, qn_g, qn_b, kn_g, kn_b,
                                                vn_g, vn_b, q_t, k_t, v_t);
  flash_k<<<dim3(32, 16), 256, 0, stream>>>(q_t, k_t, v_t, pb2, attn);
  gemm_nt_k<false><<<dim3(12, 64), 256, 0, stream>>>(attn, wo, proj, 768, 1024, nullptr, nullptr, 0.f, bo);
  ch_sumsq768_k<<<256, 768, 0, stream>>>(proj, es);
  add_scale_k<<<256, 768, 0, stream>>>(x, proj, es, bn2_g, x2);
  ch_sumsq768_k<<<256, 768, 0, stream>>>(x2, x2s);
  gemm_nt_k<true><<<dim3(24, 64), 256, 0, stream>>>(x2, w1, hbuf, 1536, 768, x2s, mbn1_g, INV_BS, b1);
  gemm_nt_k<false><<<dim3(12, 64), 256, 0, stream>>>(hbuf, w2, proj2, 768, 1536, nullptr, nullptr, 0.f, b2);
  ch_sumsq768_k<<<256, 768, 0, stream>>>(proj2, fs);
  add_scale_k<<<256, 768, 0, stream>>>(x2, proj2, fs, mbn2_g, out);

  (void)hipMemcpyAsync(out + 3145728, pair_x, (size_t)4194304 * sizeof(float),
                       hipMemcpyDeviceToDevice, stream);
}

// Round 2
// 940.252 us; speedup vs baseline: 1.6109x; 1.6109x over previous
//
#include <hip/hip_runtime.h>
#include <math.h>

#define EPS 1e-5f

typedef __attribute__((ext_vector_type(8))) short short8;
typedef __attribute__((ext_vector_type(4))) float f32x4;

namespace {

constexpr int Bn = 2, Sn = 2048, Cn = 768;
constexpr float INV_BS = 1.0f / 4096.0f;     // B*S
constexpr float INV_PAIR = 1.0f / 32768.0f;  // B*SP*SP

__device__ __forceinline__ ushort f2bf(float f) {
  uint u = __float_as_uint(f);
  u = (u + 0x7fffu + ((u >> 16) & 1u)) >> 16;
  return (ushort)u;
}

// ---- per-channel sum of squares, 128-ch (pair_x) ----
__global__ void pair_sumsq_k(const float* __restrict__ p, float* __restrict__ out) {
  int r0 = blockIdx.x * 128;
  float acc = 0.f;
  for (int r = 0; r < 128; ++r) {
    float v = p[(size_t)(r0 + r) * 128 + threadIdx.x];
    acc += v * v;
  }
  atomicAdd(&out[threadIdx.x], acc);
}

// ---- per-channel sum of squares, 768-ch ----
__global__ void ch_sumsq768_k(const float* __restrict__ a, float* __restrict__ out) {
  int r0 = blockIdx.x * 16;
  int c = threadIdx.x;
  float acc = 0.f;
  for (int r = 0; r < 16; ++r) {
    float v = a[(size_t)(r0 + r) * 768 + c];
    acc += v * v;
  }
  atomicAdd(&out[c], acc);
}

// ---- pair bias: rms_bn -> gelu -> fc [2,128] -> pb2[b,i,j,g] ----
__global__ void pair_bias_k(const float* __restrict__ p, const float* __restrict__ ps,
                            const float* __restrict__ g, const float* __restrict__ w,
                            float* __restrict__ pb2) {
  int idx = blockIdx.x * 256 + threadIdx.x;  // (b,i,j) flat, 32768 total
  const float* row = p + (size_t)idx * 128;
  float a0 = 0.f, a1 = 0.f;
  for (int c = 0; c < 128; ++c) {
    float sc = rsqrtf(ps[c] * INV_PAIR + EPS) * g[c];
    float v = row[c] * sc;
    float ge = 0.5f * v * (1.f + erff(v * 0.70710678118654752f));
    a0 += ge * w[c];
    a1 += ge * w[128 + c];
  }
  pb2[(size_t)idx * 2 + 0] = a0;
  pb2[(size_t)idx * 2 + 1] = a1;
}

// ---- generic NT GEMM: out[m,n] = act(sum_k A[m,k]*cs[k]*W[n,k] + bias[n]) ----
template <bool RELU>
__global__ __launch_bounds__(256) void gemm_nt_k(
    const float* __restrict__ A, const float* __restrict__ W,
    float* __restrict__ out, int N, int K,
    const float* __restrict__ sums, const float* __restrict__ gamma,
    float invcount, const float* __restrict__ bias) {
  __shared__ float As[32][68];
  __shared__ float Ws[32][68];
  const int m0 = blockIdx.y * 64, n0 = blockIdx.x * 64;
  const int tid = threadIdx.x;
  const int tx = tid & 15, ty = tid >> 4;
  const int row = tid >> 3;
  const int kc = (tid & 7) * 4;
  float acc[4][4] = {};
  for (int k0 = 0; k0 < K; k0 += 32) {
    float4 sc4 = {1.f, 1.f, 1.f, 1.f};
    if (sums) {
      sc4.x = rsqrtf(sums[k0 + kc + 0] * invcount + EPS) * gamma[k0 + kc + 0];
      sc4.y = rsqrtf(sums[k0 + kc + 1] * invcount + EPS) * gamma[k0 + kc + 1];
      sc4.z = rsqrtf(sums[k0 + kc + 2] * invcount + EPS) * gamma[k0 + kc + 2];
      sc4.w = rsqrtf(sums[k0 + kc + 3] * invcount + EPS) * gamma[k0 + kc + 3];
    }
#pragma unroll
    for (int half = 0; half < 2; ++half) {
      int r = row + half * 32;
      float4 av = *(const float4*)&A[(size_t)(m0 + r) * K + k0 + kc];
      if (sums) { av.x *= sc4.x; av.y *= sc4.y; av.z *= sc4.z; av.w *= sc4.w; }
      As[kc + 0][r] = av.x; As[kc + 1][r] = av.y; As[kc + 2][r] = av.z; As[kc + 3][r] = av.w;
      float4 wv = *(const float4*)&W[(size_t)(n0 + r) * K + k0 + kc];
      Ws[kc + 0][r] = wv.x; Ws[kc + 1][r] = wv.y; Ws[kc + 2][r] = wv.z; Ws[kc + 3][r] = wv.w;
    }
    __syncthreads();
#pragma unroll
    for (int k = 0; k < 32; ++k) {
      float4 a4 = *(const float4*)&As[k][ty * 4];
      float4 b4 = *(const float4*)&Ws[k][tx * 4];
      acc[0][0] += a4.x * b4.x; acc[0][1] += a4.x * b4.y; acc[0][2] += a4.x * b4.z; acc[0][3] += a4.x * b4.w;
      acc[1][0] += a4.y * b4.x; acc[1][1] += a4.y * b4.y; acc[1][2] += a4.y * b4.z; acc[1][3] += a4.y * b4.w;
      acc[2][0] += a4.z * b4.x; acc[2][1] += a4.z * b4.y; acc[2][2] += a4.z * b4.z; acc[2][3] += a4.z * b4.w;
      acc[3][0] += a4.w * b4.x; acc[3][1] += a4.w * b4.y; acc[3][2] += a4.w * b4.z; acc[3][3] += a4.w * b4.w;
    }
    __syncthreads();
  }
#pragma unroll
  for (int i = 0; i < 4; ++i) {
    float b0 = 0.f, b1 = 0.f, b2 = 0.f, b3 = 0.f;
    if (bias) {
      b0 = bias[n0 + tx * 4 + 0]; b1 = bias[n0 + tx * 4 + 1];
      b2 = bias[n0 + tx * 4 + 2]; b3 = bias[n0 + tx * 4 + 3];
    }
    float4 o;
    o.x = acc[i][0] + b0; o.y = acc[i][1] + b1; o.z = acc[i][2] + b2; o.w = acc[i][3] + b3;
    if (RELU) {
      o.x = fmaxf(o.x, 0.f); o.y = fmaxf(o.y, 0.f); o.z = fmaxf(o.z, 0.f); o.w = fmaxf(o.w, 0.f);
    }
    *(float4*)&out[(size_t)(m0 + ty * 4 + i) * N + n0 + tx * 4] = o;
  }
}

// ---- per-head LayerNorm + RoPE + transpose to [B,H,S,D], bf16 out ----
__global__ __launch_bounds__(128) void ln_rope_k(
    const float* __restrict__ qtmp, const float* __restrict__ ktmp, const float* __restrict__ vtmp,
    const float* __restrict__ qg, const float* __restrict__ qb,
    const float* __restrict__ kg, const float* __restrict__ kb,
    const float* __restrict__ vg, const float* __restrict__ vb,
    ushort* __restrict__ q_b, ushort* __restrict__ k_b, ushort* __restrict__ v_b) {
  const int bs = blockIdx.x;        // b*S+s
  const int slot = blockIdx.y;      // 0..7 q, 8..11 k, 12..15 v
  const int s = bs & (Sn - 1);
  const int b = bs >> 11;
  const int tid = threadIdx.x;
  const float* src; const float* g; const float* be; ushort* dst; bool dorope;
  if (slot < 8) {
    src = qtmp + (size_t)bs * 1024 + slot * 128;
    g = qg; be = qb;
    dst = q_b + ((size_t)(b * 8 + slot) * Sn + s) * 128;
    dorope = true;
  } else if (slot < 12) {
    int h = slot - 8;
    src = ktmp + (size_t)bs * 512 + h * 128;
    g = kg; be = kb;
    dst = k_b + ((size_t)(b * 4 + h) * Sn + s) * 128;
    dorope = true;
  } else {
    int h = slot - 12;
    src = vtmp + (size_t)bs * 512 + h * 128;
    g = vg; be = vb;
    dst = v_b + ((size_t)(b * 4 + h) * Sn + s) * 128;
    dorope = false;
  }
  __shared__ float sh[128];
  __shared__ float red[4];
  float v = src[tid];
  float sum = v;
#pragma unroll
  for (int o = 32; o >= 1; o >>= 1) sum += __shfl_xor(sum, o);
  if ((tid & 63) == 0) red[tid >> 6] = sum;
  __syncthreads();
  float mean = (red[0] + red[1]) * (1.f / 128.f);
  float d = v - mean;
  float s2 = d * d;
#pragma unroll
  for (int o = 32; o >= 1; o >>= 1) s2 += __shfl_xor(s2, o);
  if ((tid & 63) == 0) red[2 + (tid >> 6)] = s2;
  __syncthreads();
  float var = (red[2] + red[3]) * (1.f / 128.f);
  float val = d * rsqrtf(var + EPS) * g[tid] + be[tid];
  if (dorope) {
    sh[tid] = val;
    __syncthreads();
    int i = tid >> 1;
    const float kGeo = logf(1985.0f) * (1.0f / 63.0f);  // AlphaGenome schedule
    float inv = 1.0f / ((float)i + expf((float)i * kGeo));
    float th = (float)s * inv;
    float cs = cosf(th), sn = sinf(th);
    float rot = (tid & 1) ? sh[tid - 1] : -sh[tid + 1];
    val = val * cs + rot * sn;
  }
  dst[tid] = f2bf(val);
}

// ---- transpose V: [hv][2048][128] bf16 -> [hv][128][2048] bf16 ----
__global__ __launch_bounds__(256) void vtrans_k(const ushort* __restrict__ vb,
                                                ushort* __restrict__ vtt) {
  __shared__ __align__(16) ushort T[64][136];
  const int hv = blockIdx.y, s0 = blockIdx.x * 64;
  const int tid = threadIdx.x;
  const ushort* src = vb + ((size_t)hv * Sn + s0) * 128;
#pragma unroll
  for (int u = 0; u < 4; ++u) {
    int fi = u * 256 + tid;
    int r = fi >> 4, c = (fi & 15) * 8;
    *(float4*)&T[r][c] = *(const float4*)&src[(size_t)r * 128 + c];
  }
  __syncthreads();
  ushort* dst = vtt + (size_t)hv * 128 * Sn + s0;
#pragma unroll
  for (int u = 0; u < 4; ++u) {
    int fi = u * 256 + tid;
    int d = fi >> 3, t8 = (fi & 7) * 8;
    union { float4 f4; ushort us[8]; } o;
#pragma unroll
    for (int j = 0; j < 8; ++j) o.us[j] = T[t8 + j][d];
    *(float4*)&dst[(size_t)d * Sn + t8] = o.f4;
  }
}

// ---- MFMA flash attention with pair bias + tanh softcap ----
// grid (S/64, B*HQ), 4 waves; wave owns 16 q-rows; 16x16x32 bf16 MFMA.
__global__ __launch_bounds__(256) void flash_mfma_k(
    const ushort* __restrict__ qb, const ushort* __restrict__ kb,
    const ushort* __restrict__ vtt, const float* __restrict__ pb2,
    float* __restrict__ o) {
  __shared__ __align__(16) ushort Ks[64][136];   // [t][d], pad->272B rows (16B-aligned)
  __shared__ __align__(16) ushort Vt[128][72];   // [d][t]
  __shared__ __align__(16) ushort Ps[4][16][72]; // per-wave P [q][t]
  const int s0 = blockIdx.x * 64;
  const int bh = blockIdx.y;
  const int b = bh >> 3, h = bh & 7;
  const int kv = h & 3, grp = h >> 2;
  const int tid = threadIdx.x;
  const int wid = tid >> 6, lane = tid & 63;
  const int l15 = lane & 15, l4 = lane >> 4;
  const ushort* kbase = kb + (size_t)(b * 4 + kv) * Sn * 128;
  const ushort* vbase = vtt + (size_t)(b * 4 + kv) * 128 * Sn;
  const int qr0 = s0 + wid * 16;
  short8 qf[4];
#pragma unroll
  for (int kc = 0; kc < 4; ++kc)
    qf[kc] = *(const short8*)&qb[((size_t)bh * Sn + qr0 + l15) * 128 + kc * 32 + l4 * 8];
  f32x4 y[8];
#pragma unroll
  for (int i = 0; i < 8; ++i) y[i] = (f32x4){0.f, 0.f, 0.f, 0.f};
  float m[4] = {-1e30f, -1e30f, -1e30f, -1e30f};
  float lsum[4] = {0.f, 0.f, 0.f, 0.f};
  const float rs = 0.08838834764831845f;  // 1/sqrt(128)
  for (int t0 = 0; t0 < Sn; t0 += 64) {
    __syncthreads();
#pragma unroll
    for (int u = 0; u < 4; ++u) {
      int fi = u * 256 + tid;
      int r = fi >> 4, c = (fi & 15) * 8;
      *(float4*)&Ks[r][c] = *(const float4*)&kbase[(size_t)(t0 + r) * 128 + c];
      int d = fi >> 3, t8 = (fi & 7) * 8;
      *(float4*)&Vt[d][t8] = *(const float4*)&vbase[(size_t)d * Sn + t0 + t8];
    }
    __syncthreads();
    // --- QK^T ---
    f32x4 acc[4];
#pragma unroll
    for (int nb = 0; nb < 4; ++nb) acc[nb] = (f32x4){0.f, 0.f, 0.f, 0.f};
#pragma unroll
    for (int kc = 0; kc < 4; ++kc) {
#pragma unroll
      for (int nb = 0; nb < 4; ++nb) {
        short8 bk = *(const short8*)&Ks[nb * 16 + l15][kc * 32 + l4 * 8];
        acc[nb] = __builtin_amdgcn_mfma_f32_16x16x32_bf16(qf[kc], bk, acc[nb], 0, 0, 0);
      }
    }
    // --- bias + tanh softcap ---
    float sv[4][4];
#pragma unroll
    for (int nb = 0; nb < 4; ++nb) {
      float bias = pb2[(((size_t)b * 128 + (s0 >> 4) + wid) * 128 + (t0 >> 4) + nb) * 2 + grp];
#pragma unroll
      for (int r = 0; r < 4; ++r) {
        float lg = acc[nb][r] * rs + bias;
        float e = __expf(lg * 0.4f);  // e^{2x}, x=lg/5
        sv[nb][r] = 5.f - 10.f * __builtin_amdgcn_rcpf(e + 1.f);
      }
    }
    // --- online softmax (row data lives in a 16-lane group) ---
    float pr[4][4];
    float corr[4];
#pragma unroll
    for (int r = 0; r < 4; ++r) {
      float mx = fmaxf(fmaxf(sv[0][r], sv[1][r]), fmaxf(sv[2][r], sv[3][r]));
      mx = fmaxf(mx, __shfl_xor(mx, 1));
      mx = fmaxf(mx, __shfl_xor(mx, 2));
      mx = fmaxf(mx, __shfl_xor(mx, 4));
      mx = fmaxf(mx, __shfl_xor(mx, 8));
      float mn = fmaxf(m[r], mx);
      corr[r] = __expf(m[r] - mn);
      m[r] = mn;
      float psum = 0.f;
#pragma unroll
      for (int nb = 0; nb < 4; ++nb) {
        pr[nb][r] = __expf(sv[nb][r] - mn);
        psum += pr[nb][r];
      }
      lsum[r] = lsum[r] * corr[r] + psum;
    }
    f32x4 cv = {corr[0], corr[1], corr[2], corr[3]};
#pragma unroll
    for (int i = 0; i < 8; ++i) y[i] *= cv;
    // --- P -> LDS (bf16), then PV ---
#pragma unroll
    for (int nb = 0; nb < 4; ++nb)
#pragma unroll
      for (int r = 0; r < 4; ++r)
        Ps[wid][l4 * 4 + r][nb * 16 + l15] = f2bf(pr[nb][r]);
    short8 pa0 = *(const short8*)&Ps[wid][l15][l4 * 8];
    short8 pa1 = *(const short8*)&Ps[wid][l15][32 + l4 * 8];
#pragma unroll
    for (int nbd = 0; nbd < 8; ++nbd) {
      short8 v0 = *(const short8*)&Vt[nbd * 16 + l15][l4 * 8];
      short8 v1 = *(const short8*)&Vt[nbd * 16 + l15][32 + l4 * 8];
      y[nbd] = __builtin_amdgcn_mfma_f32_16x16x32_bf16(pa0, v0, y[nbd], 0, 0, 0);
      y[nbd] = __builtin_amdgcn_mfma_f32_16x16x32_bf16(pa1, v1, y[nbd], 0, 0, 0);
    }
  }
#pragma unroll
  for (int r = 0; r < 4; ++r) {
    lsum[r] += __shfl_xor(lsum[r], 1);
    lsum[r] += __shfl_xor(lsum[r], 2);
    lsum[r] += __shfl_xor(lsum[r], 4);
    lsum[r] += __shfl_xor(lsum[r], 8);
  }
  float inv[4];
#pragma unroll
  for (int r = 0; r < 4; ++r) inv[r] = 1.f / lsum[r];
#pragma unroll
  for (int nbd = 0; nbd < 8; ++nbd)
#pragma unroll
    for (int r = 0; r < 4; ++r)
      o[((size_t)bh * Sn + qr0 + l4 * 4 + r) * 128 + nbd * 16 + l15] = y[nbd][r] * inv[r];
}

// ---- out = base + delta * rsqrt(sums/4096+eps)*g ----
__global__ void add_scale_k(const float* __restrict__ base, const float* __restrict__ delta,
                            const float* __restrict__ sums, const float* __restrict__ g,
                            float* __restrict__ out) {
  const int c = threadIdx.x;
  const float sc = rsqrtf(sums[c] * INV_BS + EPS) * g[c];
  const int r0 = blockIdx.x * 16;
  for (int r = 0; r < 16; ++r) {
    size_t idx = (size_t)(r0 + r) * 768 + c;
    out[idx] = base[idx] + delta[idx] * sc;
  }
}

}  // namespace

extern "C" void kernel_launch(void* const* d_in, const int* in_sizes, int n_in,
                              void* d_out, int out_size, void* d_ws, size_t ws_size,
                              hipStream_t stream) {
  const float* x       = (const float*)d_in[0];
  const float* pair_x  = (const float*)d_in[1];
  const float* ab_bn_g = (const float*)d_in[2];
  const float* ab_fc_w = (const float*)d_in[3];
  const float* bn1_g   = (const float*)d_in[4];
  const float* wq      = (const float*)d_in[5];
  const float* wk      = (const float*)d_in[6];
  const float* wv      = (const float*)d_in[7];
  const float* qn_g    = (const float*)d_in[8];
  const float* qn_b    = (const float*)d_in[9];
  const float* kn_g    = (const float*)d_in[10];
  const float* kn_b    = (const float*)d_in[11];
  const float* vn_g    = (const float*)d_in[12];
  const float* vn_b    = (const float*)d_in[13];
  const float* wo      = (const float*)d_in[14];
  const float* bo      = (const float*)d_in[15];
  const float* bn2_g   = (const float*)d_in[16];
  const float* mbn1_g  = (const float*)d_in[17];
  const float* w1      = (const float*)d_in[18];
  const float* b1      = (const float*)d_in[19];
  const float* w2      = (const float*)d_in[20];
  const float* b2      = (const float*)d_in[21];
  const float* mbn2_g  = (const float*)d_in[22];
  float* out = (float*)d_out;
  float* ws = (float*)d_ws;

  // ws layout (floats), max 13,701,120 floats = 54.8 MiB with liveness reuse
  float* ps    = ws + 0;
  float* xs    = ws + 256;
  float* es    = ws + 1024;
  float* x2s   = ws + 2048;
  float* fs    = ws + 3072;
  float* pb2   = ws + 4096;       // 65,536
  float* qtmp  = ws + 69632;      // 4,194,304 ; later attn (f32 [b,h,s,d]), later hbuf
  float* ktmp  = ws + 4263936;    // 2,097,152 ; later proj
  float* vtmp  = ws + 6361088;    // 2,097,152
  ushort* q_b  = (ushort*)(ws + 8458240);   // bf16, 2,097,152 f-units
  ushort* k_b  = (ushort*)(ws + 10555392);  // bf16, 1,048,576
  ushort* v_b  = (ushort*)(ws + 11603968);  // bf16, 1,048,576
  ushort* v_tt = (ushort*)(ws + 12652544);  // bf16, 1,048,576
  float* attn  = qtmp;
  float* proj  = ktmp;            // spans into vtmp (dead)
  float* proj2 = ws + 6361088;    // 3,145,728 (vtmp+q_b regions, dead by then)
  float* x2    = ws + 9506816;    // 3,145,728 (q_b tail+k_b+v_b regions, dead by then)
  float* hbuf  = qtmp;            // spans into ktmp (dead)

  (void)hipMemsetAsync(ws, 0, 4096 * sizeof(float), stream);

  pair_sumsq_k<<<256, 128, 0, stream>>>(pair_x, ps);
  pair_bias_k<<<128, 256, 0, stream>>>(pair_x, ps, ab_bn_g, ab_fc_w, pb2);
  ch_sumsq768_k<<<256, 768, 0, stream>>>(x, xs);
  gemm_nt_k<false><<<dim3(16, 64), 256, 0, stream>>>(x, wq, qtmp, 1024, 768, xs, bn1_g, INV_BS, nullptr);
  gemm_nt_k<false><<<dim3(8, 64), 256, 0, stream>>>(x, wk, ktmp, 512, 768, xs, bn1_g, INV_BS, nullptr);
  gemm_nt_k<false><<<dim3(8, 64), 256, 0, stream>>>(x, wv, vtmp, 512, 768, xs, bn1_g, INV_BS, nullptr);
  ln_rope_k<<<dim3(4096, 16), 128, 0, stream>>>(qtmp, ktmp, vtmp, qn_g, qn_b, kn_g, kn_b,
                                                vn_g, vn_b, q_b, k_b, v_b);
  vtrans_k<<<dim3(32, 8), 256, 0, stream>>>(v_b, v_tt);
  flash_mfma_k<<<dim3(32, 16), 256, 0, stream>>>(q_b, k_b, v_tt, pb2, attn);
  gemm_nt_k<false><<<dim3(12, 64), 256, 0, stream>>>(attn, wo, proj, 768, 1024, nullptr, nullptr, 0.f, bo);
  ch_sumsq768_k<<<256, 768, 0, stream>>>(proj, es);
  add_scale_k<<<256, 768, 0, stream>>>(x, proj, es, bn2_g, x2);
  ch_sumsq768_k<<<256, 768, 0, stream>>>(x2, x2s);
  gemm_nt_k<true><<<dim3(24, 64), 256, 0, stream>>>(x2, w1, hbuf, 1536, 768, x2s, mbn1_g, INV_BS, b1);
  gemm_nt_k<false><<<dim3(12, 64), 256, 0, stream>>>(hbuf, w2, proj2, 768, 1536, nullptr, nullptr, 0.f, b2);
  ch_sumsq768_k<<<256, 768, 0, stream>>>(proj2, fs);
  add_scale_k<<<256, 768, 0, stream>>>(x2, proj2, fs, mbn2_g, out);

  (void)hipMemcpyAsync(out + 3145728, pair_x, (size_t)4194304 * sizeof(float),
                       hipMemcpyDeviceToDevice, stream);
}

// Round 3
// 444.881 us; speedup vs baseline: 3.4046x; 2.1135x over previous
//
#include <hip/hip_runtime.h>
#include <math.h>

#define EPS 1e-5f

typedef __attribute__((ext_vector_type(8))) short short8;
typedef __attribute__((ext_vector_type(4))) float f32x4;

namespace {

constexpr int Bn = 2, Sn = 2048, Cn = 768;
constexpr float INV_BS = 1.0f / 4096.0f;     // B*S
constexpr float INV_PAIR = 1.0f / 32768.0f;  // B*SP*SP

__device__ __forceinline__ ushort f2bf(float f) {
  uint u = __float_as_uint(f);
  u = (u + 0x7fffu + ((u >> 16) & 1u)) >> 16;
  return (ushort)u;
}

// ---- f32 -> bf16 cast, 8 elems/thread, size % 2048 == 0 ----
__global__ void castw_k(const float* __restrict__ src, ushort* __restrict__ dst) {
  int i = (blockIdx.x * 256 + threadIdx.x) * 8;
  float4 a = *(const float4*)&src[i];
  float4 b = *(const float4*)&src[i + 4];
  union { short8 s8; ushort us[8]; } o;
  o.us[0] = f2bf(a.x); o.us[1] = f2bf(a.y); o.us[2] = f2bf(a.z); o.us[3] = f2bf(a.w);
  o.us[4] = f2bf(b.x); o.us[5] = f2bf(b.y); o.us[6] = f2bf(b.z); o.us[7] = f2bf(b.w);
  *(short8*)&dst[i] = o.s8;
}

// ---- rms_bn scale + bf16 cast: o[r][c] = bf16(a[r][c]*rsqrt(sums[c]/4096+eps)*g[c]) ----
__global__ void scale_cast_k(const float* __restrict__ a, const float* __restrict__ sums,
                             const float* __restrict__ g, ushort* __restrict__ o) {
  int idx = blockIdx.x * 256 + threadIdx.x;  // 393216 total, 8 elems each, row-aligned
  int c0 = (idx % 96) * 8;
  int base = idx * 8;
  float4 v0 = *(const float4*)&a[base];
  float4 v1 = *(const float4*)&a[base + 4];
  union { short8 s8; ushort us[8]; } r;
  float vv[8] = {v0.x, v0.y, v0.z, v0.w, v1.x, v1.y, v1.z, v1.w};
#pragma unroll
  for (int j = 0; j < 8; ++j) {
    float sc = rsqrtf(sums[c0 + j] * INV_BS + EPS) * g[c0 + j];
    r.us[j] = f2bf(vv[j] * sc);
  }
  *(short8*)&o[base] = r.s8;
}

// ---- per-channel sum of squares, 128-ch (pair_x) ----
__global__ void pair_sumsq_k(const float* __restrict__ p, float* __restrict__ out) {
  int r0 = blockIdx.x * 128;
  float acc = 0.f;
  for (int r = 0; r < 128; ++r) {
    float v = p[(size_t)(r0 + r) * 128 + threadIdx.x];
    acc += v * v;
  }
  atomicAdd(&out[threadIdx.x], acc);
}

// ---- per-channel sum of squares, 768-ch ----
__global__ void ch_sumsq768_k(const float* __restrict__ a, float* __restrict__ out) {
  int r0 = blockIdx.x * 16;
  int c = threadIdx.x;
  float acc = 0.f;
  for (int r = 0; r < 16; ++r) {
    float v = a[(size_t)(r0 + r) * 768 + c];
    acc += v * v;
  }
  atomicAdd(&out[c], acc);
}

// ---- pair bias: rms_bn -> gelu -> fc [2,128] -> pb2[b,i,j,g] ----
__global__ void pair_bias_k(const float* __restrict__ p, const float* __restrict__ ps,
                            const float* __restrict__ g, const float* __restrict__ w,
                            float* __restrict__ pb2) {
  int idx = blockIdx.x * 256 + threadIdx.x;  // (b,i,j) flat, 32768 total
  const float* row = p + (size_t)idx * 128;
  float a0 = 0.f, a1 = 0.f;
  for (int c = 0; c < 128; ++c) {
    float sc = rsqrtf(ps[c] * INV_PAIR + EPS) * g[c];
    float v = row[c] * sc;
    float ge = 0.5f * v * (1.f + erff(v * 0.70710678118654752f));
    a0 += ge * w[c];
    a1 += ge * w[128 + c];
  }
  pb2[(size_t)idx * 2 + 0] = a0;
  pb2[(size_t)idx * 2 + 1] = a1;
}

// ---- bf16 NT MFMA GEMM: C[m,n] = act(sum_k A[m,k]*B[n,k] + bias[n]) ----
// A [M,K] bf16 rm, B [N,K] bf16 rm. 128x128 tile, BK=64, 4 waves (2x2), 16x16x32.
template <bool RELU, bool OUT_BF16>
__global__ __launch_bounds__(256) void gemm_bf16_k(
    const ushort* __restrict__ A, const ushort* __restrict__ B,
    void* __restrict__ Cv, int M, int N, int K,
    const float* __restrict__ bias) {
  __shared__ __align__(16) ushort As[128][72];  // +8 pad -> 144B row stride
  __shared__ __align__(16) ushort Bs[128][72];
  const int m0 = blockIdx.y * 128, n0 = blockIdx.x * 128;
  const int tid = threadIdx.x;
  const int lane = tid & 63;
  const int wid = tid >> 6;
  const int l15 = lane & 15, l4 = lane >> 4;
  const int wm = (wid >> 1) * 64, wn = (wid & 1) * 64;
  const int lr = tid >> 1;            // staging row 0..127
  const int lc = (tid & 1) * 32;      // staging col half
  f32x4 acc[4][4];
#pragma unroll
  for (int i = 0; i < 4; ++i)
#pragma unroll
    for (int j = 0; j < 4; ++j) acc[i][j] = (f32x4){0.f, 0.f, 0.f, 0.f};
  for (int k0 = 0; k0 < K; k0 += 64) {
#pragma unroll
    for (int u = 0; u < 4; ++u) {
      *(short8*)&As[lr][lc + u * 8] = *(const short8*)&A[(size_t)(m0 + lr) * K + k0 + lc + u * 8];
      *(short8*)&Bs[lr][lc + u * 8] = *(const short8*)&B[(size_t)(n0 + lr) * K + k0 + lc + u * 8];
    }
    __syncthreads();
#pragma unroll
    for (int ks = 0; ks < 2; ++ks) {
      short8 af[4], bf[4];
#pragma unroll
      for (int i = 0; i < 4; ++i) af[i] = *(const short8*)&As[wm + i * 16 + l15][ks * 32 + l4 * 8];
#pragma unroll
      for (int j = 0; j < 4; ++j) bf[j] = *(const short8*)&Bs[wn + j * 16 + l15][ks * 32 + l4 * 8];
#pragma unroll
      for (int i = 0; i < 4; ++i)
#pragma unroll
        for (int j = 0; j < 4; ++j)
          acc[i][j] = __builtin_amdgcn_mfma_f32_16x16x32_bf16(af[i], bf[j], acc[i][j], 0, 0, 0);
    }
    __syncthreads();
  }
  float* Cf = (float*)Cv;
  ushort* Cb = (ushort*)Cv;
#pragma unroll
  for (int j = 0; j < 4; ++j) {
    int col = n0 + wn + j * 16 + l15;
    float bv = bias ? bias[col] : 0.f;
#pragma unroll
    for (int i = 0; i < 4; ++i) {
      int row = m0 + wm + i * 16 + l4 * 4;
#pragma unroll
      for (int r = 0; r < 4; ++r) {
        float v = acc[i][j][r] + bv;
        if (RELU) v = fmaxf(v, 0.f);
        if (OUT_BF16) Cb[(size_t)(row + r) * N + col] = f2bf(v);
        else Cf[(size_t)(row + r) * N + col] = v;
      }
    }
  }
}

// ---- per-head LayerNorm + RoPE + transpose to [B,H,S,D], bf16 out ----
__global__ __launch_bounds__(128) void ln_rope_k(
    const float* __restrict__ qtmp, const float* __restrict__ ktmp, const float* __restrict__ vtmp,
    const float* __restrict__ qg, const float* __restrict__ qb,
    const float* __restrict__ kg, const float* __restrict__ kb,
    const float* __restrict__ vg, const float* __restrict__ vb,
    ushort* __restrict__ q_b, ushort* __restrict__ k_b, ushort* __restrict__ v_b) {
  const int bs = blockIdx.x;        // b*S+s
  const int slot = blockIdx.y;      // 0..7 q, 8..11 k, 12..15 v
  const int s = bs & (Sn - 1);
  const int b = bs >> 11;
  const int tid = threadIdx.x;
  const float* src; const float* g; const float* be; ushort* dst; bool dorope;
  if (slot < 8) {
    src = qtmp + (size_t)bs * 1024 + slot * 128;
    g = qg; be = qb;
    dst = q_b + ((size_t)(b * 8 + slot) * Sn + s) * 128;
    dorope = true;
  } else if (slot < 12) {
    int h = slot - 8;
    src = ktmp + (size_t)bs * 512 + h * 128;
    g = kg; be = kb;
    dst = k_b + ((size_t)(b * 4 + h) * Sn + s) * 128;
    dorope = true;
  } else {
    int h = slot - 12;
    src = vtmp + (size_t)bs * 512 + h * 128;
    g = vg; be = vb;
    dst = v_b + ((size_t)(b * 4 + h) * Sn + s) * 128;
    dorope = false;
  }
  __shared__ float sh[128];
  __shared__ float red[4];
  float v = src[tid];
  float sum = v;
#pragma unroll
  for (int o = 32; o >= 1; o >>= 1) sum += __shfl_xor(sum, o);
  if ((tid & 63) == 0) red[tid >> 6] = sum;
  __syncthreads();
  float mean = (red[0] + red[1]) * (1.f / 128.f);
  float d = v - mean;
  float s2 = d * d;
#pragma unroll
  for (int o = 32; o >= 1; o >>= 1) s2 += __shfl_xor(s2, o);
  if ((tid & 63) == 0) red[2 + (tid >> 6)] = s2;
  __syncthreads();
  float var = (red[2] + red[3]) * (1.f / 128.f);
  float val = d * rsqrtf(var + EPS) * g[tid] + be[tid];
  if (dorope) {
    sh[tid] = val;
    __syncthreads();
    int i = tid >> 1;
    const float kGeo = logf(1985.0f) * (1.0f / 63.0f);  // AlphaGenome schedule
    float inv = 1.0f / ((float)i + expf((float)i * kGeo));
    float th = (float)s * inv;
    float cs = cosf(th), sn = sinf(th);
    float rot = (tid & 1) ? sh[tid - 1] : -sh[tid + 1];
    val = val * cs + rot * sn;
  }
  dst[tid] = f2bf(val);
}

// ---- transpose V: [hv][2048][128] bf16 -> [hv][128][2048] bf16 ----
__global__ __launch_bounds__(256) void vtrans_k(const ushort* __restrict__ vb,
                                                ushort* __restrict__ vtt) {
  __shared__ __align__(16) ushort T[64][136];
  const int hv = blockIdx.y, s0 = blockIdx.x * 64;
  const int tid = threadIdx.x;
  const ushort* src = vb + ((size_t)hv * Sn + s0) * 128;
#pragma unroll
  for (int u = 0; u < 4; ++u) {
    int fi = u * 256 + tid;
    int r = fi >> 4, c = (fi & 15) * 8;
    *(float4*)&T[r][c] = *(const float4*)&src[(size_t)r * 128 + c];
  }
  __syncthreads();
  ushort* dst = vtt + (size_t)hv * 128 * Sn + s0;
#pragma unroll
  for (int u = 0; u < 4; ++u) {
    int fi = u * 256 + tid;
    int d = fi >> 3, t8 = (fi & 7) * 8;
    union { float4 f4; ushort us[8]; } o;
#pragma unroll
    for (int j = 0; j < 8; ++j) o.us[j] = T[t8 + j][d];
    *(float4*)&dst[(size_t)d * Sn + t8] = o.f4;
  }
}

// ---- MFMA flash attention with pair bias + tanh softcap, bf16 out ----
__global__ __launch_bounds__(256) void flash_mfma_k(
    const ushort* __restrict__ qb, const ushort* __restrict__ kb,
    const ushort* __restrict__ vtt, const float* __restrict__ pb2,
    ushort* __restrict__ o) {
  __shared__ __align__(16) ushort Ks[64][136];   // [t][d]
  __shared__ __align__(16) ushort Vt[128][72];   // [d][t]
  __shared__ __align__(16) ushort Ps[4][16][72]; // per-wave P [q][t]
  const int s0 = blockIdx.x * 64;
  const int bh = blockIdx.y;
  const int b = bh >> 3, h = bh & 7;
  const int kv = h & 3, grp = h >> 2;
  const int tid = threadIdx.x;
  const int wid = tid >> 6, lane = tid & 63;
  const int l15 = lane & 15, l4 = lane >> 4;
  const ushort* kbase = kb + (size_t)(b * 4 + kv) * Sn * 128;
  const ushort* vbase = vtt + (size_t)(b * 4 + kv) * 128 * Sn;
  const int qr0 = s0 + wid * 16;
  short8 qf[4];
#pragma unroll
  for (int kc = 0; kc < 4; ++kc)
    qf[kc] = *(const short8*)&qb[((size_t)bh * Sn + qr0 + l15) * 128 + kc * 32 + l4 * 8];
  f32x4 y[8];
#pragma unroll
  for (int i = 0; i < 8; ++i) y[i] = (f32x4){0.f, 0.f, 0.f, 0.f};
  float m[4] = {-1e30f, -1e30f, -1e30f, -1e30f};
  float lsum[4] = {0.f, 0.f, 0.f, 0.f};
  const float rs = 0.08838834764831845f;  // 1/sqrt(128)
  for (int t0 = 0; t0 < Sn; t0 += 64) {
    __syncthreads();
#pragma unroll
    for (int u = 0; u < 4; ++u) {
      int fi = u * 256 + tid;
      int r = fi >> 4, c = (fi & 15) * 8;
      *(float4*)&Ks[r][c] = *(const float4*)&kbase[(size_t)(t0 + r) * 128 + c];
      int d = fi >> 3, t8 = (fi & 7) * 8;
      *(float4*)&Vt[d][t8] = *(const float4*)&vbase[(size_t)d * Sn + t0 + t8];
    }
    __syncthreads();
    // --- QK^T ---
    f32x4 acc[4];
#pragma unroll
    for (int nb = 0; nb < 4; ++nb) acc[nb] = (f32x4){0.f, 0.f, 0.f, 0.f};
#pragma unroll
    for (int kc = 0; kc < 4; ++kc) {
#pragma unroll
      for (int nb = 0; nb < 4; ++nb) {
        short8 bk = *(const short8*)&Ks[nb * 16 + l15][kc * 32 + l4 * 8];
        acc[nb] = __builtin_amdgcn_mfma_f32_16x16x32_bf16(qf[kc], bk, acc[nb], 0, 0, 0);
      }
    }
    // --- bias + tanh softcap ---
    float sv[4][4];
#pragma unroll
    for (int nb = 0; nb < 4; ++nb) {
      float bias = pb2[(((size_t)b * 128 + (s0 >> 4) + wid) * 128 + (t0 >> 4) + nb) * 2 + grp];
#pragma unroll
      for (int r = 0; r < 4; ++r) {
        float lg = acc[nb][r] * rs + bias;
        float e = __expf(lg * 0.4f);  // e^{2x}, x=lg/5
        sv[nb][r] = 5.f - 10.f * __builtin_amdgcn_rcpf(e + 1.f);
      }
    }
    // --- online softmax (row data lives in a 16-lane group) ---
    float pr[4][4];
    float corr[4];
#pragma unroll
    for (int r = 0; r < 4; ++r) {
      float mx = fmaxf(fmaxf(sv[0][r], sv[1][r]), fmaxf(sv[2][r], sv[3][r]));
      mx = fmaxf(mx, __shfl_xor(mx, 1));
      mx = fmaxf(mx, __shfl_xor(mx, 2));
      mx = fmaxf(mx, __shfl_xor(mx, 4));
      mx = fmaxf(mx, __shfl_xor(mx, 8));
      float mn = fmaxf(m[r], mx);
      corr[r] = __expf(m[r] - mn);
      m[r] = mn;
      float psum = 0.f;
#pragma unroll
      for (int nb = 0; nb < 4; ++nb) {
        pr[nb][r] = __expf(sv[nb][r] - mn);
        psum += pr[nb][r];
      }
      lsum[r] = lsum[r] * corr[r] + psum;
    }
    f32x4 cv = {corr[0], corr[1], corr[2], corr[3]};
#pragma unroll
    for (int i = 0; i < 8; ++i) y[i] *= cv;
    // --- P -> LDS (bf16), then PV ---
#pragma unroll
    for (int nb = 0; nb < 4; ++nb)
#pragma unroll
      for (int r = 0; r < 4; ++r)
        Ps[wid][l4 * 4 + r][nb * 16 + l15] = f2bf(pr[nb][r]);
    short8 pa0 = *(const short8*)&Ps[wid][l15][l4 * 8];
    short8 pa1 = *(const short8*)&Ps[wid][l15][32 + l4 * 8];
#pragma unroll
    for (int nbd = 0; nbd < 8; ++nbd) {
      short8 v0 = *(const short8*)&Vt[nbd * 16 + l15][l4 * 8];
      short8 v1 = *(const short8*)&Vt[nbd * 16 + l15][32 + l4 * 8];
      y[nbd] = __builtin_amdgcn_mfma_f32_16x16x32_bf16(pa0, v0, y[nbd], 0, 0, 0);
      y[nbd] = __builtin_amdgcn_mfma_f32_16x16x32_bf16(pa1, v1, y[nbd], 0, 0, 0);
    }
  }
#pragma unroll
  for (int r = 0; r < 4; ++r) {
    lsum[r] += __shfl_xor(lsum[r], 1);
    lsum[r] += __shfl_xor(lsum[r], 2);
    lsum[r] += __shfl_xor(lsum[r], 4);
    lsum[r] += __shfl_xor(lsum[r], 8);
  }
  float inv[4];
#pragma unroll
  for (int r = 0; r < 4; ++r) inv[r] = 1.f / lsum[r];
#pragma unroll
  for (int nbd = 0; nbd < 8; ++nbd)
#pragma unroll
    for (int r = 0; r < 4; ++r)
      o[((size_t)bh * Sn + qr0 + l4 * 4 + r) * 128 + nbd * 16 + l15] = f2bf(y[nbd][r] * inv[r]);
}

// ---- out = base + delta * rsqrt(sums/4096+eps)*g ----
__global__ void add_scale_k(const float* __restrict__ base, const float* __restrict__ delta,
                            const float* __restrict__ sums, const float* __restrict__ g,
                            float* __restrict__ out) {
  const int c = threadIdx.x;
  const float sc = rsqrtf(sums[c] * INV_BS + EPS) * g[c];
  const int r0 = blockIdx.x * 16;
  for (int r = 0; r < 16; ++r) {
    size_t idx = (size_t)(r0 + r) * 768 + c;
    out[idx] = base[idx] + delta[idx] * sc;
  }
}

}  // namespace

extern "C" void kernel_launch(void* const* d_in, const int* in_sizes, int n_in,
                              void* d_out, int out_size, void* d_ws, size_t ws_size,
                              hipStream_t stream) {
  const float* x       = (const float*)d_in[0];
  const float* pair_x  = (const float*)d_in[1];
  const float* ab_bn_g = (const float*)d_in[2];
  const float* ab_fc_w = (const float*)d_in[3];
  const float* bn1_g   = (const float*)d_in[4];
  const float* wq      = (const float*)d_in[5];
  const float* wk      = (const float*)d_in[6];
  const float* wv      = (const float*)d_in[7];
  const float* qn_g    = (const float*)d_in[8];
  const float* qn_b    = (const float*)d_in[9];
  const float* kn_g    = (const float*)d_in[10];
  const float* kn_b    = (const float*)d_in[11];
  const float* vn_g    = (const float*)d_in[12];
  const float* vn_b    = (const float*)d_in[13];
  const float* wo      = (const float*)d_in[14];
  const float* bo      = (const float*)d_in[15];
  const float* bn2_g   = (const float*)d_in[16];
  const float* mbn1_g  = (const float*)d_in[17];
  const float* w1      = (const float*)d_in[18];
  const float* b1      = (const float*)d_in[19];
  const float* w2      = (const float*)d_in[20];
  const float* b2      = (const float*)d_in[21];
  const float* mbn2_g  = (const float*)d_in[22];
  float* out = (float*)d_out;
  float* ws = (float*)d_ws;

  // ws layout (f32 units), liveness-reused, max 16,584,704 f = 66.3 MiB
  float* ps    = ws + 0;
  float* xs    = ws + 256;
  float* es    = ws + 1024;
  float* x2s   = ws + 2048;
  float* fs    = ws + 3072;
  float* pb2   = ws + 4096;                   // 65,536
  ushort* wq_b = (ushort*)(ws + 69632);       // 786,432 bf16
  ushort* wk_b = (ushort*)(ws + 462848);      // 393,216
  ushort* wv_b = (ushort*)(ws + 659456);      // 393,216
  ushort* wo_b = (ushort*)(ws + 856064);      // 786,432
  ushort* w1_b = (ushort*)(ws + 1249280);     // 1,179,648
  ushort* w2_b = (ushort*)(ws + 1839104);     // 1,179,648
  ushort* xn_b = (ushort*)(ws + 2428928);     // 3,145,728 bf16 ; later x2n_b
  float* qtmp  = ws + 4001792;                // 4,194,304 f32
  float* ktmp  = ws + 8196096;                // 2,097,152
  float* vtmp  = ws + 10293248;               // 2,097,152
  ushort* q_b  = (ushort*)(ws + 12390400);    // 4,194,304 bf16
  ushort* k_b  = (ushort*)(ws + 14487552);    // 2,097,152 bf16
  ushort* v_b  = (ushort*)(ws + 15536128);    // 2,097,152 bf16
  ushort* v_tt = (ushort*)(ws + 8196096);     // over ktmp (dead post-ln_rope)
  ushort* attn_b = (ushort*)(ws + 4001792);   // over qtmp (dead post-ln_rope)
  float* proj  = ws + 10293248;               // 3,145,728 over vtmp+q_b (dead post-flash)
  float* x2    = ws + 13438976;               // 3,145,728 over q_b tail+k_b+v_b
  ushort* x2n_b = xn_b;                       // xn_b dead after qkv gemms
  ushort* hbuf_b = (ushort*)(ws + 6098944);   // 6,291,456 bf16 over qtmp tail+v_tt (dead)
  float* proj2 = ws + 10293248;               // over proj (dead after add_scale)

  (void)hipMemsetAsync(ws, 0, 4096 * sizeof(float), stream);

  // weight casts
  castw_k<<<384, 256, 0, stream>>>(wq, wq_b);
  castw_k<<<192, 256, 0, stream>>>(wk, wk_b);
  castw_k<<<192, 256, 0, stream>>>(wv, wv_b);
  castw_k<<<384, 256, 0, stream>>>(wo, wo_b);
  castw_k<<<576, 256, 0, stream>>>(w1, w1_b);
  castw_k<<<576, 256, 0, stream>>>(w2, w2_b);

  pair_sumsq_k<<<256, 128, 0, stream>>>(pair_x, ps);
  pair_bias_k<<<128, 256, 0, stream>>>(pair_x, ps, ab_bn_g, ab_fc_w, pb2);
  ch_sumsq768_k<<<256, 768, 0, stream>>>(x, xs);
  scale_cast_k<<<1536, 256, 0, stream>>>(x, xs, bn1_g, xn_b);
  gemm_bf16_k<false, false><<<dim3(8, 32), 256, 0, stream>>>(xn_b, wq_b, qtmp, 4096, 1024, 768, nullptr);
  gemm_bf16_k<false, false><<<dim3(4, 32), 256, 0, stream>>>(xn_b, wk_b, ktmp, 4096, 512, 768, nullptr);
  gemm_bf16_k<false, false><<<dim3(4, 32), 256, 0, stream>>>(xn_b, wv_b, vtmp, 4096, 512, 768, nullptr);
  ln_rope_k<<<dim3(4096, 16), 128, 0, stream>>>(qtmp, ktmp, vtmp, qn_g, qn_b, kn_g, kn_b,
                                                vn_g, vn_b, q_b, k_b, v_b);
  vtrans_k<<<dim3(32, 8), 256, 0, stream>>>(v_b, v_tt);
  flash_mfma_k<<<dim3(32, 16), 256, 0, stream>>>(q_b, k_b, v_tt, pb2, attn_b);
  gemm_bf16_k<false, false><<<dim3(6, 32), 256, 0, stream>>>(attn_b, wo_b, proj, 4096, 768, 1024, bo);
  ch_sumsq768_k<<<256, 768, 0, stream>>>(proj, es);
  add_scale_k<<<256, 768, 0, stream>>>(x, proj, es, bn2_g, x2);
  ch_sumsq768_k<<<256, 768, 0, stream>>>(x2, x2s);
  scale_cast_k<<<1536, 256, 0, stream>>>(x2, x2s, mbn1_g, x2n_b);
  gemm_bf16_k<true, true><<<dim3(12, 32), 256, 0, stream>>>(x2n_b, w1_b, hbuf_b, 4096, 1536, 768, b1);
  gemm_bf16_k<false, false><<<dim3(6, 32), 256, 0, stream>>>(hbuf_b, w2_b, proj2, 4096, 768, 1536, b2);
  ch_sumsq768_k<<<256, 768, 0, stream>>>(proj2, fs);
  add_scale_k<<<256, 768, 0, stream>>>(x2, proj2, fs, mbn2_g, out);

  (void)hipMemcpyAsync(out + 3145728, pair_x, (size_t)4194304 * sizeof(float),
                       hipMemcpyDeviceToDevice, stream);
}